// Round 7
// baseline (339.182 us; speedup 1.0000x reference)
//
#include <hip/hip_runtime.h>

#define N_NODES 50000
#define N_EDGES 800000
#define NBUCK 196       // ceil(50000/256) buckets of 256 nodes
#define PBLK 391        // ceil(800000/2048) partition blocks
#define CAP 5120        // bucket window capacity
#define NG 196          // node groups of 256 for sliced gathers

typedef unsigned short ushort_t;
typedef short short8 __attribute__((ext_vector_type(8)));
typedef short short4v __attribute__((ext_vector_type(4)));
typedef float floatx4 __attribute__((ext_vector_type(4)));

__device__ __forceinline__ float bf2f(ushort_t u) {
    unsigned v = ((unsigned)u) << 16;
    return __builtin_bit_cast(float, v);
}
__device__ __forceinline__ ushort_t f2bf(float f) {
    unsigned u = __builtin_bit_cast(unsigned, f);
    unsigned r = (u + 0x7FFFu + ((u >> 16) & 1u)) >> 16;  // RNE
    return (ushort_t)r;
}
__device__ __forceinline__ float4 ld4(const float* p) { return *(const float4*)p; }

// ---------------- prep: cvt_x + cvt_w + bucket cursor init ----------------
__global__ __launch_bounds__(256) void prep_kernel(
    const float* __restrict__ x,
    const float* __restrict__ W1_rel, const float* __restrict__ W1_root,
    const float* __restrict__ W2_rel, const float* __restrict__ W2_root,
    const float* __restrict__ Wmu_rel, const float* __restrict__ Wls_rel,
    const float* __restrict__ Wmu_root, const float* __restrict__ Wls_root,
    ushort_t* __restrict__ ax, ushort_t* __restrict__ B1t,
    ushort_t* __restrict__ B2t, ushort_t* __restrict__ B3t,
    int* __restrict__ bcursor) {
    int idx = blockIdx.x * blockDim.x + threadIdx.x;
    if (idx < 400000) {                       // ax[n,64:128] = bf16(x[n,:])
        int n = idx >> 3, c = (idx & 7) * 8;
        float4 v0 = ld4(x + (size_t)n * 64 + c);
        float4 v1 = ld4(x + (size_t)n * 64 + c + 4);
        short8 o;
        o[0] = f2bf(v0.x); o[1] = f2bf(v0.y); o[2] = f2bf(v0.z); o[3] = f2bf(v0.w);
        o[4] = f2bf(v1.x); o[5] = f2bf(v1.y); o[6] = f2bf(v1.z); o[7] = f2bf(v1.w);
        *(short8*)(ax + (size_t)n * 128 + 64 + c) = o;
    } else if (idx < 506496) {                // transposed bf16 weights
        int j = idx - 400000;
        if (j < 32768) {
            int n = j >> 7, k = j & 127;
            float v = (k < 64) ? W1_rel[k * 256 + n] : W1_root[(k - 64) * 256 + n];
            B1t[j] = f2bf(v);
        } else if (j < 98304) {
            int jj = j - 32768;
            int n = jj >> 8, k = jj & 255;
            float v = (n < 128) ? W2_rel[k * 128 + n] : W2_root[k * 128 + (n - 128)];
            B2t[jj] = f2bf(v);
        } else {
            int jj = j - 98304;
            int n = jj >> 7, k = jj & 127;
            const float* W = (n < 16) ? Wmu_rel : (n < 32) ? Wls_rel : (n < 48) ? Wmu_root : Wls_root;
            B3t[jj] = f2bf(W[k * 16 + (n & 15)]);
        }
    } else if (idx < 506496 + NBUCK) {
        int b = idx - 506496;
        bcursor[b] = b * CAP;
    }
}

// ---------------- single-pass partition into fixed bucket windows ----------------
__global__ __launch_bounds__(256) void partition_kernel(
    const int* __restrict__ src, const int* __restrict__ dst,
    int* __restrict__ bcursor, unsigned* __restrict__ pairbuf) {
    __shared__ int h[NBUCK];
    __shared__ int cur[NBUCK];
    const int tid = threadIdx.x;
    for (int i = tid; i < NBUCK; i += 256) h[i] = 0;
    __syncthreads();
    const int base = blockIdx.x * 2048;
    int d[8];
    #pragma unroll
    for (int j = 0; j < 8; ++j) {
        int e = base + j * 256 + tid;
        if (e < N_EDGES) { d[j] = dst[e]; atomicAdd(&h[d[j] >> 8], 1); }
        else d[j] = -1;
    }
    __syncthreads();
    for (int i = tid; i < NBUCK; i += 256) {
        int c = h[i];
        cur[i] = c ? atomicAdd(&bcursor[i], c) : 0;
    }
    __syncthreads();
    #pragma unroll
    for (int j = 0; j < 8; ++j) {
        int e = base + j * 256 + tid;
        if (e < N_EDGES) {
            int dd = d[j];
            int slot = atomicAdd(&cur[dd >> 8], 1);
            pairbuf[slot] = (unsigned)src[e] | ((unsigned)(dd & 255) << 16);
        }
    }
}

// per-bucket: node histogram + scan -> row_beg/row_end/dinv; LDS-cursor fill of 16-bit eidx
__global__ __launch_bounds__(256) void fill_bucket_kernel(
    const unsigned* __restrict__ pairbuf, const int* __restrict__ bcursor,
    int* __restrict__ row_beg, int* __restrict__ row_end,
    float* __restrict__ dinv, ushort_t* __restrict__ eidx) {
    __shared__ int h[256];
    __shared__ int sm[256];
    __shared__ int cur[256];
    const int b = blockIdx.x, tid = threadIdx.x;
    const int beg = b * CAP, end = bcursor[b];
    h[tid] = 0;
    __syncthreads();
    for (int i = beg + tid; i < end; i += 256)
        atomicAdd(&h[pairbuf[i] >> 16], 1);
    __syncthreads();
    int c = h[tid];
    sm[tid] = c;
    __syncthreads();
    #pragma unroll
    for (int off = 1; off < 256; off <<= 1) {
        int t = (tid >= off) ? sm[tid - off] : 0;
        __syncthreads();
        sm[tid] += t;
        __syncthreads();
    }
    int exc = beg + sm[tid] - c;
    int node = b * 256 + tid;
    if (node < N_NODES) {
        row_beg[node] = exc;
        row_end[node] = exc + c;
        dinv[node] = c > 0 ? 1.0f / (float)c : 0.0f;
    }
    cur[tid] = exc;
    __syncthreads();
    for (int i = beg + tid; i < end; i += 256) {
        unsigned v = pairbuf[i];
        int slot = atomicAdd(&cur[v >> 16], 1);
        eidx[slot] = (ushort_t)(v & 0xFFFFu);
    }
}

// ---------------- gather 1 (XCD-sliced, 8 chunks x 8 ch): ax[:,0:64] = mean of ax[:,64:128] ----------------
__global__ __launch_bounds__(256) void gather1s_kernel(
    const int* __restrict__ row_beg, const int* __restrict__ row_end,
    const ushort_t* __restrict__ eidx, const float* __restrict__ dinv,
    ushort_t* __restrict__ ax) {
    const int c = blockIdx.x & 7;           // chunk -> XCD (round-robin heuristic)
    const int n = (blockIdx.x >> 3) * 256 + threadIdx.x;
    if (n >= N_NODES) return;
    const int beg = row_beg[n], end = row_end[n];
    float a0[8] = {}, a1[8] = {};
    int j = beg;
    for (; j + 1 < end; j += 2) {
        int s0 = eidx[j], s1 = eidx[j + 1];
        short8 v0 = *(const short8*)(ax + (size_t)s0 * 128 + 64 + c * 8);
        short8 v1 = *(const short8*)(ax + (size_t)s1 * 128 + 64 + c * 8);
        #pragma unroll
        for (int i = 0; i < 8; ++i) { a0[i] += bf2f((ushort_t)v0[i]); a1[i] += bf2f((ushort_t)v1[i]); }
    }
    if (j < end) {
        int s0 = eidx[j];
        short8 v0 = *(const short8*)(ax + (size_t)s0 * 128 + 64 + c * 8);
        #pragma unroll
        for (int i = 0; i < 8; ++i) a0[i] += bf2f((ushort_t)v0[i]);
    }
    float d = dinv[n];
    short8 o;
    #pragma unroll
    for (int i = 0; i < 8; ++i) o[i] = f2bf((a0[i] + a1[i]) * d);
    *(short8*)(ax + (size_t)n * 128 + c * 8) = o;
}

// ---------------- gemm1: h1 = relu(ax @ [W1_rel;W1_root] + b1), K=128, N=256 (ny looped) ----------------
__global__ __launch_bounds__(256) void gemm1_mfma(
    const ushort_t* __restrict__ A, const ushort_t* __restrict__ Bt,
    const float* __restrict__ b1, ushort_t* __restrict__ h1) {
    constexpr int K = 128, KP = K + 8;
    __shared__ ushort_t Bs[64 * KP];
    const int tid = threadIdx.x;
    const int w = tid >> 6, lane = tid & 63;
    const int ln = lane & 15, quad = lane >> 4;
    const int rowbase = blockIdx.x * 64 + w * 16;
    int r = rowbase + ln; if (r > N_NODES - 1) r = N_NODES - 1;
    short8 a[4];
    #pragma unroll
    for (int s = 0; s < 4; ++s)
        a[s] = *(const short8*)(A + (size_t)r * K + s * 32 + quad * 8);
    const int r0 = rowbase + quad * 4;
    for (int ny = 0; ny < 4; ++ny) {
        __syncthreads();
        for (int i = tid; i < 64 * 16; i += 256) {
            int row = i >> 4, off = (i & 15) * 8;
            *(short8*)(Bs + row * KP + off) = *(const short8*)(Bt + (size_t)(ny * 64 + row) * K + off);
        }
        __syncthreads();
        floatx4 acc[4] = {};
        #pragma unroll
        for (int f = 0; f < 4; ++f) {
            const ushort_t* bp = Bs + (f * 16 + ln) * KP + quad * 8;
            #pragma unroll
            for (int s = 0; s < 4; ++s) {
                short8 b = *(const short8*)(bp + s * 32);
                acc[f] = __builtin_amdgcn_mfma_f32_16x16x32_bf16(a[s], b, acc[f], 0, 0, 0);
            }
        }
        #pragma unroll
        for (int f = 0; f < 4; ++f) {
            int n = ny * 64 + f * 16 + ln;
            float bias = b1[n];
            #pragma unroll
            for (int g = 0; g < 4; ++g) {
                int rr = r0 + g;
                if (rr >= N_NODES) continue;
                h1[(size_t)rr * 256 + n] = f2bf(fmaxf(acc[f][g] + bias, 0.0f));
            }
        }
    }
}

// ---------------- gemm2: [t2s | r2s] = h1 @ [W2_rel | W2_root], sliced bf16 outputs ----------------
__global__ __launch_bounds__(256) void gemm2_mfma(
    const ushort_t* __restrict__ A, const ushort_t* __restrict__ Bt,
    ushort_t* __restrict__ t2s, ushort_t* __restrict__ r2s) {
    constexpr int K = 256, KP = K + 8;
    __shared__ ushort_t Bs[64 * KP];
    const int tid = threadIdx.x;
    const int w = tid >> 6, lane = tid & 63;
    const int ln = lane & 15, quad = lane >> 4;
    const int rowbase = blockIdx.x * 64 + w * 16;
    int r = rowbase + ln; if (r > N_NODES - 1) r = N_NODES - 1;
    short8 a[8];
    #pragma unroll
    for (int s = 0; s < 8; ++s)
        a[s] = *(const short8*)(A + (size_t)r * K + s * 32 + quad * 8);
    const int r0 = rowbase + quad * 4;
    for (int ny = 0; ny < 4; ++ny) {
        __syncthreads();
        for (int i = tid; i < 64 * 32; i += 256) {
            int row = i >> 5, off = (i & 31) * 8;
            *(short8*)(Bs + row * KP + off) = *(const short8*)(Bt + (size_t)(ny * 64 + row) * K + off);
        }
        __syncthreads();
        floatx4 acc[4] = {};
        #pragma unroll
        for (int f = 0; f < 4; ++f) {
            const ushort_t* bp = Bs + (f * 16 + ln) * KP + quad * 8;
            #pragma unroll
            for (int s = 0; s < 8; ++s) {
                short8 b = *(const short8*)(bp + s * 32);
                acc[f] = __builtin_amdgcn_mfma_f32_16x16x32_bf16(a[s], b, acc[f], 0, 0, 0);
            }
        }
        #pragma unroll
        for (int f = 0; f < 4; ++f) {
            int n = ny * 64 + f * 16 + ln;
            #pragma unroll
            for (int g = 0; g < 4; ++g) {
                int rr = r0 + g;
                if (rr >= N_NODES) continue;
                ushort_t v = f2bf(acc[f][g]);
                if (n < 128) t2s[(size_t)(n >> 4) * 800000 + (size_t)rr * 16 + (n & 15)] = v;
                else {
                    int m = n - 128;
                    r2s[(size_t)(m >> 4) * 800000 + (size_t)rr * 16 + (m & 15)] = v;
                }
            }
        }
    }
}

// ---------------- gather 2 (XCD-sliced, 8 chunks x 16 ch): h2s = relu(mean(t2s) + r2s + b2) ----------------
__global__ __launch_bounds__(256) void gather2s_kernel(
    const ushort_t* __restrict__ t2s, const ushort_t* __restrict__ r2s,
    const int* __restrict__ row_beg, const int* __restrict__ row_end,
    const ushort_t* __restrict__ eidx, const float* __restrict__ dinv,
    const float* __restrict__ b2, ushort_t* __restrict__ h2s) {
    const int c = blockIdx.x & 7;
    const int n = (blockIdx.x >> 3) * 256 + threadIdx.x;
    if (n >= N_NODES) return;
    const ushort_t* tb = t2s + (size_t)c * 800000;
    const int beg = row_beg[n], end = row_end[n];
    float a0[16] = {}, a1[16] = {};
    int j = beg;
    for (; j + 1 < end; j += 2) {
        const ushort_t* p0 = tb + (size_t)eidx[j] * 16;
        const ushort_t* p1 = tb + (size_t)eidx[j + 1] * 16;
        short8 u0 = *(const short8*)(p0), u1 = *(const short8*)(p0 + 8);
        short8 w0 = *(const short8*)(p1), w1 = *(const short8*)(p1 + 8);
        #pragma unroll
        for (int i = 0; i < 8; ++i) {
            a0[i] += bf2f((ushort_t)u0[i]); a0[8 + i] += bf2f((ushort_t)u1[i]);
            a1[i] += bf2f((ushort_t)w0[i]); a1[8 + i] += bf2f((ushort_t)w1[i]);
        }
    }
    if (j < end) {
        const ushort_t* p0 = tb + (size_t)eidx[j] * 16;
        short8 u0 = *(const short8*)(p0), u1 = *(const short8*)(p0 + 8);
        #pragma unroll
        for (int i = 0; i < 8; ++i) { a0[i] += bf2f((ushort_t)u0[i]); a0[8 + i] += bf2f((ushort_t)u1[i]); }
    }
    float d = dinv[n];
    const ushort_t* rp = r2s + (size_t)c * 800000 + (size_t)n * 16;
    short8 rv0 = *(const short8*)(rp), rv1 = *(const short8*)(rp + 8);
    short8 o0, o1;
    #pragma unroll
    for (int i = 0; i < 8; ++i) {
        float b_lo = b2[c * 16 + i], b_hi = b2[c * 16 + 8 + i];
        o0[i] = f2bf(fmaxf((a0[i] + a1[i]) * d + bf2f((ushort_t)rv0[i]) + b_lo, 0.0f));
        o1[i] = f2bf(fmaxf((a0[8 + i] + a1[8 + i]) * d + bf2f((ushort_t)rv1[i]) + b_hi, 0.0f));
    }
    ushort_t* hp = h2s + (size_t)c * 800000 + (size_t)n * 16;
    *(short8*)(hp) = o0;
    *(short8*)(hp + 8) = o1;
}

// ---------------- gemm3: [tmls | rmls] = h2s @ B3t (sliced in, sliced out) ----------------
__global__ __launch_bounds__(256) void gemm3_mfma(
    const ushort_t* __restrict__ h2s, const ushort_t* __restrict__ B3t,
    ushort_t* __restrict__ tmls, float* __restrict__ rmls) {
    constexpr int K = 128, KP = K + 8;
    __shared__ ushort_t As[64 * KP];
    __shared__ ushort_t Bs[64 * KP];
    const int tid = threadIdx.x;
    const int nb = blockIdx.x * 64;
    // stage As from sliced h2s: As[nl][c*16..+16]
    for (int i = tid; i < 64 * 8; i += 256) {
        int nl = i >> 3, c = i & 7;
        int node = nb + nl; if (node > N_NODES - 1) node = N_NODES - 1;
        const ushort_t* sp = h2s + (size_t)c * 800000 + (size_t)node * 16;
        *(short8*)(As + nl * KP + c * 16) = *(const short8*)(sp);
        *(short8*)(As + nl * KP + c * 16 + 8) = *(const short8*)(sp + 8);
    }
    // stage B3t (64 x 128)
    for (int i = tid; i < 64 * 16; i += 256) {
        int row = i >> 4, off = (i & 15) * 8;
        *(short8*)(Bs + row * KP + off) = *(const short8*)(B3t + row * 128 + off);
    }
    __syncthreads();
    const int w = tid >> 6, lane = tid & 63;
    const int ln = lane & 15, quad = lane >> 4;
    short8 a[4];
    #pragma unroll
    for (int s = 0; s < 4; ++s)
        a[s] = *(const short8*)(As + (w * 16 + ln) * KP + s * 32 + quad * 8);
    floatx4 acc[4] = {};
    #pragma unroll
    for (int f = 0; f < 4; ++f) {
        const ushort_t* bp = Bs + (f * 16 + ln) * KP + quad * 8;
        #pragma unroll
        for (int s = 0; s < 4; ++s) {
            short8 b = *(const short8*)(bp + s * 32);
            acc[f] = __builtin_amdgcn_mfma_f32_16x16x32_bf16(a[s], b, acc[f], 0, 0, 0);
        }
    }
    const int r0 = nb + w * 16 + quad * 4;
    #pragma unroll
    for (int f = 0; f < 4; ++f) {
        int ncol = f * 16 + ln;
        #pragma unroll
        for (int g = 0; g < 4; ++g) {
            int rr = r0 + g;
            if (rr >= N_NODES) continue;
            float v = acc[f][g];
            if (ncol < 32) tmls[(size_t)(ncol >> 2) * 200000 + (size_t)rr * 4 + (ncol & 3)] = f2bf(v);
            else {
                int m = ncol - 32;
                rmls[(size_t)(m >> 2) * 200000 + (size_t)rr * 4 + (m & 3)] = v;
            }
        }
    }
}

// ---------------- gather 3 (XCD-sliced, 8 chunks x 4 ch) + combine + split write ----------------
__global__ __launch_bounds__(256) void gather3s_kernel(
    const ushort_t* __restrict__ tmls, const float* __restrict__ rmls,
    const int* __restrict__ row_beg, const int* __restrict__ row_end,
    const ushort_t* __restrict__ eidx, const float* __restrict__ dinv,
    const float* __restrict__ bmu, const float* __restrict__ bls,
    float* __restrict__ out) {
    const int c = blockIdx.x & 7;
    const int n = (blockIdx.x >> 3) * 256 + threadIdx.x;
    if (n >= N_NODES) return;
    const ushort_t* tb = tmls + (size_t)c * 200000;
    const int beg = row_beg[n], end = row_end[n];
    float a0[4] = {}, a1[4] = {};
    int j = beg;
    for (; j + 1 < end; j += 2) {
        short4v v0 = *(const short4v*)(tb + (size_t)eidx[j] * 4);
        short4v v1 = *(const short4v*)(tb + (size_t)eidx[j + 1] * 4);
        #pragma unroll
        for (int i = 0; i < 4; ++i) { a0[i] += bf2f((ushort_t)v0[i]); a1[i] += bf2f((ushort_t)v1[i]); }
    }
    if (j < end) {
        short4v v0 = *(const short4v*)(tb + (size_t)eidx[j] * 4);
        #pragma unroll
        for (int i = 0; i < 4; ++i) a0[i] += bf2f((ushort_t)v0[i]);
    }
    float d = dinv[n];
    float4 rv = ld4(rmls + (size_t)c * 200000 + (size_t)n * 4);
    const float* bias = (c < 4) ? (bmu + c * 4) : (bls + (c - 4) * 4);
    float4 bv = ld4(bias);
    float4 res;
    res.x = (a0[0] + a1[0]) * d + rv.x + bv.x;
    res.y = (a0[1] + a1[1]) * d + rv.y + bv.y;
    res.z = (a0[2] + a1[2]) * d + rv.z + bv.z;
    res.w = (a0[3] + a1[3]) * d + rv.w + bv.w;
    float* base = (c < 4) ? (out + (size_t)n * 16 + c * 4)
                          : (out + 800000u + (size_t)n * 16 + (c - 4) * 4);
    *(float4*)base = res;
}

extern "C" void kernel_launch(void* const* d_in, const int* in_sizes, int n_in,
                              void* d_out, int out_size, void* d_ws, size_t ws_size,
                              hipStream_t stream) {
    const float* x       = (const float*)d_in[0];
    const float* W1_rel  = (const float*)d_in[1];
    const float* b1      = (const float*)d_in[2];
    const float* W1_root = (const float*)d_in[3];
    const float* W2_rel  = (const float*)d_in[4];
    const float* b2      = (const float*)d_in[5];
    const float* W2_root = (const float*)d_in[6];
    const float* Wmu_rel = (const float*)d_in[7];
    const float* bmu     = (const float*)d_in[8];
    const float* Wmu_root= (const float*)d_in[9];
    const float* Wls_rel = (const float*)d_in[10];
    const float* bls     = (const float*)d_in[11];
    const float* Wls_root= (const float*)d_in[12];
    const int*   ei      = (const int*)d_in[13];
    const int* src = ei;
    const int* dst = ei + N_EDGES;

    // ---- workspace layout ----
    int*      bcursor = (int*)d_ws;                      //       256
    int*      row_beg = bcursor + 256;                   //    50,048
    int*      row_end = row_beg + 50048;                 //    50,048
    unsigned* pairbuf = (unsigned*)(row_end + 50048);    // 1,003,520
    ushort_t* eidx    = (ushort_t*)(pairbuf + 1003520);  // 1,003,520 ush
    float*    dinv    = (float*)(eidx + 1003520);        //    50,000
    ushort_t* ax   = (ushort_t*)(dinv + 50000);          //  6,400,000  [N,128]: [agg | x]
    ushort_t* h1   = ax + 6400000;                       // 12,800,000  [N,256]
    ushort_t* t2s  = h1 + 12800000;                      //  6,400,000  [8][N][16]
    ushort_t* r2s  = t2s + 6400000;                      //  6,400,000  [8][N][16]
    ushort_t* h2s  = r2s + 6400000;                      //  6,400,000  [8][N][16]
    ushort_t* tmls = h2s + 6400000;                      //  1,600,000  [8][N][4]
    ushort_t* B1t  = tmls + 1600000;                     //     32,768
    ushort_t* B2t  = B1t + 32768;                        //     65,536
    ushort_t* B3t  = B2t + 65536;                        //      8,192
    float* rmls    = (float*)(B3t + 8192);               //  1,600,000  [8][N][4] f32
    float* out     = (float*)d_out;

    // ---- prep + CSR build ----
    prep_kernel<<<1980, 256, 0, stream>>>(x, W1_rel, W1_root, W2_rel, W2_root,
                                          Wmu_rel, Wls_rel, Wmu_root, Wls_root,
                                          ax, B1t, B2t, B3t, bcursor);
    partition_kernel<<<PBLK, 256, 0, stream>>>(src, dst, bcursor, pairbuf);
    fill_bucket_kernel<<<NBUCK, 256, 0, stream>>>(pairbuf, bcursor, row_beg, row_end, dinv, eidx);

    // ---- layer 1 ----
    gather1s_kernel<<<NG * 8, 256, 0, stream>>>(row_beg, row_end, eidx, dinv, ax);
    gemm1_mfma<<<782, 256, 0, stream>>>(ax, B1t, b1, h1);

    // ---- layer 2 ----
    gemm2_mfma<<<782, 256, 0, stream>>>(h1, B2t, t2s, r2s);
    gather2s_kernel<<<NG * 8, 256, 0, stream>>>(t2s, r2s, row_beg, row_end, eidx, dinv, b2, h2s);

    // ---- mu / logstd ----
    gemm3_mfma<<<782, 256, 0, stream>>>(h2s, B3t, tmls, rmls);
    gather3s_kernel<<<NG * 8, 256, 0, stream>>>(tmls, rmls, row_beg, row_end, eidx, dinv, bmu, bls, out);
}

// Round 8
// 264.276 us; speedup vs baseline: 1.2834x; 1.2834x over previous
//
#include <hip/hip_runtime.h>

#define N_NODES 50000
#define N_EDGES 800000
#define NBUCK 196       // ceil(50000/256) buckets of 256 nodes
#define PBLK 391        // ceil(800000/2048) partition blocks
#define CAP 5120        // bucket window capacity

typedef unsigned short ushort_t;
typedef short short8 __attribute__((ext_vector_type(8)));
typedef float floatx4 __attribute__((ext_vector_type(4)));

__device__ __forceinline__ float bf2f(ushort_t u) {
    unsigned v = ((unsigned)u) << 16;
    return __builtin_bit_cast(float, v);
}
__device__ __forceinline__ ushort_t f2bf(float f) {
    unsigned u = __builtin_bit_cast(unsigned, f);
    unsigned r = (u + 0x7FFFu + ((u >> 16) & 1u)) >> 16;  // RNE
    return (ushort_t)r;
}
__device__ __forceinline__ float4 ld4(const float* p) { return *(const float4*)p; }

// ---------------- prep: cvt_x + cvt_w + bucket cursor init ----------------
__global__ __launch_bounds__(256) void prep_kernel(
    const float* __restrict__ x,
    const float* __restrict__ W1_rel, const float* __restrict__ W1_root,
    const float* __restrict__ W2_rel, const float* __restrict__ W2_root,
    const float* __restrict__ Wmu_rel, const float* __restrict__ Wls_rel,
    const float* __restrict__ Wmu_root, const float* __restrict__ Wls_root,
    ushort_t* __restrict__ ax, ushort_t* __restrict__ B1t,
    ushort_t* __restrict__ B2t, ushort_t* __restrict__ B3t,
    int* __restrict__ bcursor) {
    int idx = blockIdx.x * blockDim.x + threadIdx.x;
    if (idx < 400000) {                       // ax[n,64:128] = bf16(x[n,:])
        int n = idx >> 3, c = (idx & 7) * 8;
        float4 v0 = ld4(x + (size_t)n * 64 + c);
        float4 v1 = ld4(x + (size_t)n * 64 + c + 4);
        short8 o;
        o[0] = f2bf(v0.x); o[1] = f2bf(v0.y); o[2] = f2bf(v0.z); o[3] = f2bf(v0.w);
        o[4] = f2bf(v1.x); o[5] = f2bf(v1.y); o[6] = f2bf(v1.z); o[7] = f2bf(v1.w);
        *(short8*)(ax + (size_t)n * 128 + 64 + c) = o;
    } else if (idx < 506496) {                // transposed bf16 weights
        int j = idx - 400000;
        if (j < 32768) {
            int n = j >> 7, k = j & 127;
            float v = (k < 64) ? W1_rel[k * 256 + n] : W1_root[(k - 64) * 256 + n];
            B1t[j] = f2bf(v);
        } else if (j < 98304) {
            int jj = j - 32768;
            int n = jj >> 8, k = jj & 255;
            float v = (n < 128) ? W2_rel[k * 128 + n] : W2_root[k * 128 + (n - 128)];
            B2t[jj] = f2bf(v);
        } else {
            int jj = j - 98304;
            int n = jj >> 7, k = jj & 127;
            const float* W = (n < 16) ? Wmu_rel : (n < 32) ? Wls_rel : (n < 48) ? Wmu_root : Wls_root;
            B3t[jj] = f2bf(W[k * 16 + (n & 15)]);
        }
    } else if (idx < 506496 + NBUCK) {
        int b = idx - 506496;
        bcursor[b] = b * CAP;
    }
}

// ---------------- single-pass partition into fixed bucket windows ----------------
__global__ __launch_bounds__(256) void partition_kernel(
    const int* __restrict__ src, const int* __restrict__ dst,
    int* __restrict__ bcursor, unsigned* __restrict__ pairbuf) {
    __shared__ int h[NBUCK];
    __shared__ int cur[NBUCK];
    const int tid = threadIdx.x;
    for (int i = tid; i < NBUCK; i += 256) h[i] = 0;
    __syncthreads();
    const int base = blockIdx.x * 2048;
    int d[8];
    #pragma unroll
    for (int j = 0; j < 8; ++j) {
        int e = base + j * 256 + tid;
        if (e < N_EDGES) { d[j] = dst[e]; atomicAdd(&h[d[j] >> 8], 1); }
        else d[j] = -1;
    }
    __syncthreads();
    for (int i = tid; i < NBUCK; i += 256) {
        int c = h[i];
        cur[i] = c ? atomicAdd(&bcursor[i], c) : 0;
    }
    __syncthreads();
    #pragma unroll
    for (int j = 0; j < 8; ++j) {
        int e = base + j * 256 + tid;
        if (e < N_EDGES) {
            int dd = d[j];
            int slot = atomicAdd(&cur[dd >> 8], 1);
            pairbuf[slot] = (unsigned)src[e] | ((unsigned)(dd & 255) << 16);
        }
    }
}

// per-bucket: node histogram + scan -> row_beg/row_end/dinv; LDS-cursor fill of 16-bit eidx
__global__ __launch_bounds__(256) void fill_bucket_kernel(
    const unsigned* __restrict__ pairbuf, const int* __restrict__ bcursor,
    int* __restrict__ row_beg, int* __restrict__ row_end,
    float* __restrict__ dinv, ushort_t* __restrict__ eidx) {
    __shared__ int h[256];
    __shared__ int sm[256];
    __shared__ int cur[256];
    const int b = blockIdx.x, tid = threadIdx.x;
    const int beg = b * CAP, end = bcursor[b];
    h[tid] = 0;
    __syncthreads();
    for (int i = beg + tid; i < end; i += 256)
        atomicAdd(&h[pairbuf[i] >> 16], 1);
    __syncthreads();
    int c = h[tid];
    sm[tid] = c;
    __syncthreads();
    #pragma unroll
    for (int off = 1; off < 256; off <<= 1) {
        int t = (tid >= off) ? sm[tid - off] : 0;
        __syncthreads();
        sm[tid] += t;
        __syncthreads();
    }
    int exc = beg + sm[tid] - c;
    int node = b * 256 + tid;
    if (node < N_NODES) {
        row_beg[node] = exc;
        row_end[node] = exc + c;
        dinv[node] = c > 0 ? 1.0f / (float)c : 0.0f;
    }
    cur[tid] = exc;
    __syncthreads();
    for (int i = beg + tid; i < end; i += 256) {
        unsigned v = pairbuf[i];
        int slot = atomicAdd(&cur[v >> 16], 1);
        eidx[slot] = (ushort_t)(v & 0xFFFFu);
    }
}

// ---------------- fused gather1 + gemm1 ----------------
// Per block: 64 nodes. Phase 1: As[nl][0:64]=mean-gather(x_nb), As[nl][64:128]=x_n (bf16).
// Phase 2: h1 = relu(As @ B1t + b1), N=256 via ny loop; B-frags straight from global (cache-hot).
__global__ __launch_bounds__(256) void g1gemm1_kernel(
    const ushort_t* __restrict__ ax, const ushort_t* __restrict__ B1t,
    const int* __restrict__ row_beg, const int* __restrict__ row_end,
    const ushort_t* __restrict__ eidx, const float* __restrict__ dinv,
    const float* __restrict__ b1, ushort_t* __restrict__ h1) {
    constexpr int KP = 136;
    __shared__ ushort_t As[64 * KP];
    const int tid = threadIdx.x;
    const int nb = blockIdx.x * 64;
    // phase 1: 4 threads/node, 16 agg channels each
    {
        const int nl = tid >> 2, lane = tid & 3;
        int node = nb + nl; if (node > N_NODES - 1) node = N_NODES - 1;
        const int beg = row_beg[node], end = row_end[node];
        float a0[16] = {}, a1[16] = {};
        int j = beg;
        for (; j + 1 < end; j += 2) {
            const ushort_t* p0 = ax + (size_t)eidx[j] * 128 + 64 + lane * 16;
            const ushort_t* p1 = ax + (size_t)eidx[j + 1] * 128 + 64 + lane * 16;
            short8 u0 = *(const short8*)(p0), u1 = *(const short8*)(p0 + 8);
            short8 w0 = *(const short8*)(p1), w1 = *(const short8*)(p1 + 8);
            #pragma unroll
            for (int i = 0; i < 8; ++i) {
                a0[i] += bf2f((ushort_t)u0[i]); a0[8 + i] += bf2f((ushort_t)u1[i]);
                a1[i] += bf2f((ushort_t)w0[i]); a1[8 + i] += bf2f((ushort_t)w1[i]);
            }
        }
        if (j < end) {
            const ushort_t* p0 = ax + (size_t)eidx[j] * 128 + 64 + lane * 16;
            short8 u0 = *(const short8*)(p0), u1 = *(const short8*)(p0 + 8);
            #pragma unroll
            for (int i = 0; i < 8; ++i) { a0[i] += bf2f((ushort_t)u0[i]); a0[8 + i] += bf2f((ushort_t)u1[i]); }
        }
        float d = dinv[node];
        short8 o0, o1;
        #pragma unroll
        for (int i = 0; i < 8; ++i) {
            o0[i] = f2bf((a0[i] + a1[i]) * d);
            o1[i] = f2bf((a0[8 + i] + a1[8 + i]) * d);
        }
        *(short8*)(As + nl * KP + lane * 16) = o0;
        *(short8*)(As + nl * KP + lane * 16 + 8) = o1;
        // own x row -> root half
        const ushort_t* xp = ax + (size_t)node * 128 + 64 + lane * 16;
        *(short8*)(As + nl * KP + 64 + lane * 16) = *(const short8*)(xp);
        *(short8*)(As + nl * KP + 64 + lane * 16 + 8) = *(const short8*)(xp + 8);
    }
    __syncthreads();
    // phase 2: MFMA, A from LDS, B from global (64KB table, L1/L2-hot)
    const int w = tid >> 6, lane = tid & 63;
    const int ln = lane & 15, quad = lane >> 4;
    short8 a[4];
    #pragma unroll
    for (int s = 0; s < 4; ++s)
        a[s] = *(const short8*)(As + (w * 16 + ln) * KP + s * 32 + quad * 8);
    const int rowbase = nb + w * 16;
    const int r0 = rowbase + quad * 4;
    for (int ny = 0; ny < 4; ++ny) {
        floatx4 acc[4] = {};
        #pragma unroll
        for (int f = 0; f < 4; ++f) {
            const ushort_t* bp = B1t + (size_t)(ny * 64 + f * 16 + ln) * 128 + quad * 8;
            #pragma unroll
            for (int s = 0; s < 4; ++s) {
                short8 b = *(const short8*)(bp + s * 32);
                acc[f] = __builtin_amdgcn_mfma_f32_16x16x32_bf16(a[s], b, acc[f], 0, 0, 0);
            }
        }
        #pragma unroll
        for (int f = 0; f < 4; ++f) {
            int n = ny * 64 + f * 16 + ln;
            float bias = b1[n];
            #pragma unroll
            for (int g = 0; g < 4; ++g) {
                int rr = r0 + g;
                if (rr >= N_NODES) continue;
                h1[(size_t)rr * 256 + n] = f2bf(fmaxf(acc[f][g] + bias, 0.0f));
            }
        }
    }
}

// ---------------- gemm2: [t2 | r2] = h1 @ [W2_rel | W2_root], both bf16 [N][128] ----------------
__global__ __launch_bounds__(256) void gemm2_mfma(
    const ushort_t* __restrict__ A, const ushort_t* __restrict__ Bt,
    ushort_t* __restrict__ t2, ushort_t* __restrict__ r2) {
    constexpr int K = 256, KP = K + 8;
    __shared__ ushort_t Bs[64 * KP];
    const int tid = threadIdx.x;
    const int w = tid >> 6, lane = tid & 63;
    const int ln = lane & 15, quad = lane >> 4;
    const int rowbase = blockIdx.x * 64 + w * 16;
    int r = rowbase + ln; if (r > N_NODES - 1) r = N_NODES - 1;
    short8 a[8];
    #pragma unroll
    for (int s = 0; s < 8; ++s)
        a[s] = *(const short8*)(A + (size_t)r * K + s * 32 + quad * 8);
    const int r0 = rowbase + quad * 4;
    for (int ny = 0; ny < 4; ++ny) {
        __syncthreads();
        for (int i = tid; i < 64 * 32; i += 256) {
            int row = i >> 5, off = (i & 31) * 8;
            *(short8*)(Bs + row * KP + off) = *(const short8*)(Bt + (size_t)(ny * 64 + row) * K + off);
        }
        __syncthreads();
        floatx4 acc[4] = {};
        #pragma unroll
        for (int f = 0; f < 4; ++f) {
            const ushort_t* bp = Bs + (f * 16 + ln) * KP + quad * 8;
            #pragma unroll
            for (int s = 0; s < 8; ++s) {
                short8 b = *(const short8*)(bp + s * 32);
                acc[f] = __builtin_amdgcn_mfma_f32_16x16x32_bf16(a[s], b, acc[f], 0, 0, 0);
            }
        }
        #pragma unroll
        for (int f = 0; f < 4; ++f) {
            int n = ny * 64 + f * 16 + ln;
            #pragma unroll
            for (int g = 0; g < 4; ++g) {
                int rr = r0 + g;
                if (rr >= N_NODES) continue;
                ushort_t v = f2bf(acc[f][g]);
                if (n < 128) t2[(size_t)rr * 128 + n] = v;
                else r2[(size_t)rr * 128 + (n - 128)] = v;
            }
        }
    }
}

// ---------------- fused gather2 + combine + gemm3 ----------------
// Per block: 64 nodes. Phase 1: h2 row = relu(mean-gather(t2) + r2 + b2) -> LDS As (bf16).
// Phase 2: [tml | rml] = As @ B3t via MFMA; B-frags from global (16KB table, cache-hot).
__global__ __launch_bounds__(256) void g2g3_kernel(
    const ushort_t* __restrict__ t2, const ushort_t* __restrict__ r2,
    const int* __restrict__ row_beg, const int* __restrict__ row_end,
    const ushort_t* __restrict__ eidx, const float* __restrict__ dinv,
    const float* __restrict__ b2, const ushort_t* __restrict__ B3t,
    ushort_t* __restrict__ tml, float* __restrict__ rml) {
    constexpr int KP = 136;
    __shared__ ushort_t As[64 * KP];
    const int tid = threadIdx.x;
    const int nb = blockIdx.x * 64;
    // phase 1: 4 threads/node, 32 ch each
    {
        const int nl = tid >> 2, lane = tid & 3;
        int node = nb + nl; if (node > N_NODES - 1) node = N_NODES - 1;
        const int beg = row_beg[node], end = row_end[node];
        float acc[32];
        #pragma unroll
        for (int i = 0; i < 32; ++i) acc[i] = 0.0f;
        for (int j = beg; j < end; ++j) {
            const ushort_t* tp = t2 + (size_t)eidx[j] * 128 + lane * 32;
            short8 v0 = *(const short8*)(tp);
            short8 v1 = *(const short8*)(tp + 8);
            short8 v2 = *(const short8*)(tp + 16);
            short8 v3 = *(const short8*)(tp + 24);
            #pragma unroll
            for (int i = 0; i < 8; ++i) {
                acc[i]      += bf2f((ushort_t)v0[i]);
                acc[8 + i]  += bf2f((ushort_t)v1[i]);
                acc[16 + i] += bf2f((ushort_t)v2[i]);
                acc[24 + i] += bf2f((ushort_t)v3[i]);
            }
        }
        float d = dinv[node];
        const ushort_t* rp = r2 + (size_t)node * 128 + lane * 32;
        const float* bp = b2 + lane * 32;
        ushort_t* ap = As + nl * KP + lane * 32;
        #pragma unroll
        for (int q = 0; q < 4; ++q) {
            short8 rv = *(const short8*)(rp + q * 8);
            float4 ba = ld4(bp + q * 8), bb = ld4(bp + q * 8 + 4);
            float bc[8] = {ba.x, ba.y, ba.z, ba.w, bb.x, bb.y, bb.z, bb.w};
            short8 o;
            #pragma unroll
            for (int i = 0; i < 8; ++i)
                o[i] = f2bf(fmaxf(acc[q * 8 + i] * d + bf2f((ushort_t)rv[i]) + bc[i], 0.0f));
            *(short8*)(ap + q * 8) = o;
        }
    }
    __syncthreads();
    // phase 2: MFMA, M=64, N=64, K=128; B from global
    const int w = tid >> 6, lane64 = tid & 63;
    const int ln = lane64 & 15, quad = lane64 >> 4;
    short8 a[4];
    #pragma unroll
    for (int s = 0; s < 4; ++s)
        a[s] = *(const short8*)(As + (w * 16 + ln) * KP + s * 32 + quad * 8);
    floatx4 accv[4] = {};
    #pragma unroll
    for (int f = 0; f < 4; ++f) {
        const ushort_t* bpp = B3t + (size_t)(f * 16 + ln) * 128 + quad * 8;
        #pragma unroll
        for (int s = 0; s < 4; ++s) {
            short8 b = *(const short8*)(bpp + s * 32);
            accv[f] = __builtin_amdgcn_mfma_f32_16x16x32_bf16(a[s], b, accv[f], 0, 0, 0);
        }
    }
    const int r0 = nb + w * 16 + quad * 4;
    #pragma unroll
    for (int f = 0; f < 4; ++f) {
        int ncol = f * 16 + ln;
        #pragma unroll
        for (int g = 0; g < 4; ++g) {
            int rr = r0 + g;
            if (rr >= N_NODES) continue;
            float v = accv[f][g];
            if (ncol < 32) tml[(size_t)rr * 32 + ncol] = f2bf(v);
            else rml[(size_t)rr * 32 + (ncol - 32)] = v;
        }
    }
}

// ---------------- gather 3 (fused combine + split write) ----------------
__global__ __launch_bounds__(256) void gather3_kernel(
    const ushort_t* __restrict__ tml, const float* __restrict__ rml,
    const int* __restrict__ row_beg, const int* __restrict__ row_end,
    const ushort_t* __restrict__ eidx, const float* __restrict__ dinv,
    const float* __restrict__ bmu, const float* __restrict__ bls,
    float* __restrict__ out) {
    const int lane = threadIdx.x & 3;
    const int nl = threadIdx.x >> 2;
    const int n = blockIdx.x * 64 + nl;
    if (n >= N_NODES) return;
    const int beg = row_beg[n], end = row_end[n];
    float a0[8] = {}, a1[8] = {};
    int j = beg;
    for (; j + 1 < end; j += 2) {
        int s0 = eidx[j], s1 = eidx[j + 1];
        short8 v0 = *(const short8*)(tml + (size_t)s0 * 32 + lane * 8);
        short8 v1 = *(const short8*)(tml + (size_t)s1 * 32 + lane * 8);
        #pragma unroll
        for (int i = 0; i < 8; ++i) { a0[i] += bf2f((ushort_t)v0[i]); a1[i] += bf2f((ushort_t)v1[i]); }
    }
    if (j < end) {
        int s0 = eidx[j];
        short8 v0 = *(const short8*)(tml + (size_t)s0 * 32 + lane * 8);
        #pragma unroll
        for (int i = 0; i < 8; ++i) a0[i] += bf2f((ushort_t)v0[i]);
    }
    float d = dinv[n];
    const float* bias = (lane < 2) ? (bmu + lane * 8) : (bls + (lane - 2) * 8);
    float4 ra = ld4(rml + (size_t)n * 32 + lane * 8);
    float4 rb = ld4(rml + (size_t)n * 32 + lane * 8 + 4);
    float4 ba = ld4(bias);
    float4 bb = ld4(bias + 4);
    float rr[8] = {ra.x, ra.y, ra.z, ra.w, rb.x, rb.y, rb.z, rb.w};
    float bc[8] = {ba.x, ba.y, ba.z, ba.w, bb.x, bb.y, bb.z, bb.w};
    float res[8];
    #pragma unroll
    for (int i = 0; i < 8; ++i) res[i] = (a0[i] + a1[i]) * d + rr[i] + bc[i];
    float* base = (lane < 2) ? (out + (size_t)n * 16 + lane * 8)
                             : (out + 800000u + (size_t)n * 16 + (lane - 2) * 8);
    *(float4*)(base) = make_float4(res[0], res[1], res[2], res[3]);
    *(float4*)(base + 4) = make_float4(res[4], res[5], res[6], res[7]);
}

extern "C" void kernel_launch(void* const* d_in, const int* in_sizes, int n_in,
                              void* d_out, int out_size, void* d_ws, size_t ws_size,
                              hipStream_t stream) {
    const float* x       = (const float*)d_in[0];
    const float* W1_rel  = (const float*)d_in[1];
    const float* b1      = (const float*)d_in[2];
    const float* W1_root = (const float*)d_in[3];
    const float* W2_rel  = (const float*)d_in[4];
    const float* b2      = (const float*)d_in[5];
    const float* W2_root = (const float*)d_in[6];
    const float* Wmu_rel = (const float*)d_in[7];
    const float* bmu     = (const float*)d_in[8];
    const float* Wmu_root= (const float*)d_in[9];
    const float* Wls_rel = (const float*)d_in[10];
    const float* bls     = (const float*)d_in[11];
    const float* Wls_root= (const float*)d_in[12];
    const int*   ei      = (const int*)d_in[13];
    const int* src = ei;
    const int* dst = ei + N_EDGES;

    // ---- workspace layout ----
    int*      bcursor = (int*)d_ws;                      //       256
    int*      row_beg = bcursor + 256;                   //    50,048
    int*      row_end = row_beg + 50048;                 //    50,048
    unsigned* pairbuf = (unsigned*)(row_end + 50048);    // 1,003,520
    ushort_t* eidx    = (ushort_t*)(pairbuf + 1003520);  // 1,003,520 ush
    float*    dinv    = (float*)(eidx + 1003520);        //    50,000
    ushort_t* ax   = (ushort_t*)(dinv + 50000);          //  6,400,000  [N,128]: [agg | x] (lo unused now)
    ushort_t* h1   = ax + 6400000;                       // 12,800,000  [N,256]
    ushort_t* t2   = h1 + 12800000;                      //  6,400,000  [N,128] bf16
    ushort_t* r2   = t2 + 6400000;                       //  6,400,000  [N,128] bf16
    ushort_t* tml  = r2 + 6400000;                       //  1,600,000  [N,32]  bf16
    ushort_t* B1t  = tml + 1600000;                      //     32,768
    ushort_t* B2t  = B1t + 32768;                        //     65,536
    ushort_t* B3t  = B2t + 65536;                        //      8,192
    float* rml     = (float*)(B3t + 8192);               //  1,600,000  [N,32] f32
    float* out     = (float*)d_out;

    // ---- prep + CSR build ----
    prep_kernel<<<1980, 256, 0, stream>>>(x, W1_rel, W1_root, W2_rel, W2_root,
                                          Wmu_rel, Wls_rel, Wmu_root, Wls_root,
                                          ax, B1t, B2t, B3t, bcursor);
    partition_kernel<<<PBLK, 256, 0, stream>>>(src, dst, bcursor, pairbuf);
    fill_bucket_kernel<<<NBUCK, 256, 0, stream>>>(pairbuf, bcursor, row_beg, row_end, dinv, eidx);

    // ---- layer 1 (fused gather + GEMM) ----
    g1gemm1_kernel<<<782, 256, 0, stream>>>(ax, B1t, row_beg, row_end, eidx, dinv, b1, h1);

    // ---- layer 2 ----
    gemm2_mfma<<<782, 256, 0, stream>>>(h1, B2t, t2, r2);
    g2g3_kernel<<<782, 256, 0, stream>>>(t2, r2, row_beg, row_end, eidx, dinv, b2, B3t, tml, rml);

    // ---- mu / logstd final aggregation ----
    gather3_kernel<<<782, 256, 0, stream>>>(tml, rml, row_beg, row_end, eidx, dinv, bmu, bls, out);
}

// Round 9
// 245.287 us; speedup vs baseline: 1.3828x; 1.0774x over previous
//
#include <hip/hip_runtime.h>

#define N_NODES 50000
#define N_EDGES 800000
#define NBUCK 196       // ceil(50000/256) buckets of 256 nodes
#define PBLK 391        // ceil(800000/2048) partition blocks
#define CAP 5120        // bucket window capacity

typedef unsigned short ushort_t;
typedef short short8 __attribute__((ext_vector_type(8)));
typedef float floatx4 __attribute__((ext_vector_type(4)));

__device__ __forceinline__ float bf2f(ushort_t u) {
    unsigned v = ((unsigned)u) << 16;
    return __builtin_bit_cast(float, v);
}
__device__ __forceinline__ ushort_t f2bf(float f) {
    unsigned u = __builtin_bit_cast(unsigned, f);
    unsigned r = (u + 0x7FFFu + ((u >> 16) & 1u)) >> 16;  // RNE
    return (ushort_t)r;
}
__device__ __forceinline__ float4 ld4(const float* p) { return *(const float4*)p; }

// ---------------- prep: cvt_x + cvt_w + bucket cursor init ----------------
__global__ __launch_bounds__(256) void prep_kernel(
    const float* __restrict__ x,
    const float* __restrict__ W1_rel, const float* __restrict__ W1_root,
    const float* __restrict__ W2_rel, const float* __restrict__ W2_root,
    const float* __restrict__ Wmu_rel, const float* __restrict__ Wls_rel,
    const float* __restrict__ Wmu_root, const float* __restrict__ Wls_root,
    ushort_t* __restrict__ ax, ushort_t* __restrict__ B1t,
    ushort_t* __restrict__ B2t, ushort_t* __restrict__ B3t,
    int* __restrict__ bcursor) {
    int idx = blockIdx.x * blockDim.x + threadIdx.x;
    if (idx < 400000) {                       // ax[n,64:128] = bf16(x[n,:])
        int n = idx >> 3, c = (idx & 7) * 8;
        float4 v0 = ld4(x + (size_t)n * 64 + c);
        float4 v1 = ld4(x + (size_t)n * 64 + c + 4);
        short8 o;
        o[0] = f2bf(v0.x); o[1] = f2bf(v0.y); o[2] = f2bf(v0.z); o[3] = f2bf(v0.w);
        o[4] = f2bf(v1.x); o[5] = f2bf(v1.y); o[6] = f2bf(v1.z); o[7] = f2bf(v1.w);
        *(short8*)(ax + (size_t)n * 128 + 64 + c) = o;
    } else if (idx < 506496) {                // transposed bf16 weights
        int j = idx - 400000;
        if (j < 32768) {
            int n = j >> 7, k = j & 127;
            float v = (k < 64) ? W1_rel[k * 256 + n] : W1_root[(k - 64) * 256 + n];
            B1t[j] = f2bf(v);
        } else if (j < 98304) {
            int jj = j - 32768;
            int n = jj >> 8, k = jj & 255;
            float v = (n < 128) ? W2_rel[k * 128 + n] : W2_root[k * 128 + (n - 128)];
            B2t[jj] = f2bf(v);
        } else {
            int jj = j - 98304;
            int n = jj >> 7, k = jj & 127;
            const float* W = (n < 16) ? Wmu_rel : (n < 32) ? Wls_rel : (n < 48) ? Wmu_root : Wls_root;
            B3t[jj] = f2bf(W[k * 16 + (n & 15)]);
        }
    } else if (idx < 506496 + NBUCK) {
        int b = idx - 506496;
        bcursor[b] = b * CAP;
    }
}

// ---------------- single-pass partition into fixed bucket windows ----------------
__global__ __launch_bounds__(256) void partition_kernel(
    const int* __restrict__ src, const int* __restrict__ dst,
    int* __restrict__ bcursor, unsigned* __restrict__ pairbuf) {
    __shared__ int h[NBUCK];
    __shared__ int cur[NBUCK];
    const int tid = threadIdx.x;
    for (int i = tid; i < NBUCK; i += 256) h[i] = 0;
    __syncthreads();
    const int base = blockIdx.x * 2048;
    int d[8];
    #pragma unroll
    for (int j = 0; j < 8; ++j) {
        int e = base + j * 256 + tid;
        if (e < N_EDGES) { d[j] = dst[e]; atomicAdd(&h[d[j] >> 8], 1); }
        else d[j] = -1;
    }
    __syncthreads();
    for (int i = tid; i < NBUCK; i += 256) {
        int c = h[i];
        cur[i] = c ? atomicAdd(&bcursor[i], c) : 0;
    }
    __syncthreads();
    #pragma unroll
    for (int j = 0; j < 8; ++j) {
        int e = base + j * 256 + tid;
        if (e < N_EDGES) {
            int dd = d[j];
            int slot = atomicAdd(&cur[dd >> 8], 1);
            pairbuf[slot] = (unsigned)src[e] | ((unsigned)(dd & 255) << 16);
        }
    }
}

// per-bucket: node histogram + scan -> row_beg/row_end/dinv; LDS-cursor fill of 16-bit eidx
__global__ __launch_bounds__(256) void fill_bucket_kernel(
    const unsigned* __restrict__ pairbuf, const int* __restrict__ bcursor,
    int* __restrict__ row_beg, int* __restrict__ row_end,
    float* __restrict__ dinv, ushort_t* __restrict__ eidx) {
    __shared__ int h[256];
    __shared__ int sm[256];
    __shared__ int cur[256];
    const int b = blockIdx.x, tid = threadIdx.x;
    const int beg = b * CAP, end = bcursor[b];
    h[tid] = 0;
    __syncthreads();
    for (int i = beg + tid; i < end; i += 256)
        atomicAdd(&h[pairbuf[i] >> 16], 1);
    __syncthreads();
    int c = h[tid];
    sm[tid] = c;
    __syncthreads();
    #pragma unroll
    for (int off = 1; off < 256; off <<= 1) {
        int t = (tid >= off) ? sm[tid - off] : 0;
        __syncthreads();
        sm[tid] += t;
        __syncthreads();
    }
    int exc = beg + sm[tid] - c;
    int node = b * 256 + tid;
    if (node < N_NODES) {
        row_beg[node] = exc;
        row_end[node] = exc + c;
        dinv[node] = c > 0 ? 1.0f / (float)c : 0.0f;
    }
    cur[tid] = exc;
    __syncthreads();
    for (int i = beg + tid; i < end; i += 256) {
        unsigned v = pairbuf[i];
        int slot = atomicAdd(&cur[v >> 16], 1);
        eidx[slot] = (ushort_t)(v & 0xFFFFu);
    }
}

// ---------------- gather 1: ax[:, 0:64] = mean-gather of ax[:, 64:128] ----------------
// 1563 blocks, 32 nodes/block, 8 lanes/node (16B each), 4-edge unroll
__global__ __launch_bounds__(256) void gather1_kernel(
    const int* __restrict__ row_beg, const int* __restrict__ row_end,
    const ushort_t* __restrict__ eidx, const float* __restrict__ dinv,
    ushort_t* __restrict__ ax) {
    const int lane = threadIdx.x & 7;
    const int nl = threadIdx.x >> 3;
    const int n = blockIdx.x * 32 + nl;
    if (n >= N_NODES) return;
    const int beg = row_beg[n], end = row_end[n];
    float a0[8] = {}, a1[8] = {}, a2[8] = {}, a3[8] = {};
    int j = beg;
    for (; j + 3 < end; j += 4) {
        int s0 = eidx[j], s1 = eidx[j + 1], s2 = eidx[j + 2], s3 = eidx[j + 3];
        short8 v0 = *(const short8*)(ax + (size_t)s0 * 128 + 64 + lane * 8);
        short8 v1 = *(const short8*)(ax + (size_t)s1 * 128 + 64 + lane * 8);
        short8 v2 = *(const short8*)(ax + (size_t)s2 * 128 + 64 + lane * 8);
        short8 v3 = *(const short8*)(ax + (size_t)s3 * 128 + 64 + lane * 8);
        #pragma unroll
        for (int i = 0; i < 8; ++i) {
            a0[i] += bf2f((ushort_t)v0[i]); a1[i] += bf2f((ushort_t)v1[i]);
            a2[i] += bf2f((ushort_t)v2[i]); a3[i] += bf2f((ushort_t)v3[i]);
        }
    }
    for (; j < end; ++j) {
        int s0 = eidx[j];
        short8 v0 = *(const short8*)(ax + (size_t)s0 * 128 + 64 + lane * 8);
        #pragma unroll
        for (int i = 0; i < 8; ++i) a0[i] += bf2f((ushort_t)v0[i]);
    }
    float d = dinv[n];
    short8 o;
    #pragma unroll
    for (int i = 0; i < 8; ++i) o[i] = f2bf(((a0[i] + a1[i]) + (a2[i] + a3[i])) * d);
    *(short8*)(ax + (size_t)n * 128 + lane * 8) = o;
}

// ---------------- gemm1: h1 = relu(ax @ B1t + b1), K=128, N=256, ny loop (A loaded once) ----------------
__global__ __launch_bounds__(256) void gemm1_mfma(
    const ushort_t* __restrict__ A, const ushort_t* __restrict__ Bt,
    const float* __restrict__ b1, ushort_t* __restrict__ h1) {
    constexpr int K = 128, KP = K + 8;
    __shared__ ushort_t Bs[64 * KP];
    const int tid = threadIdx.x;
    const int w = tid >> 6, lane = tid & 63;
    const int ln = lane & 15, quad = lane >> 4;
    const int rowbase = blockIdx.x * 64 + w * 16;
    int r = rowbase + ln; if (r > N_NODES - 1) r = N_NODES - 1;
    short8 a[4];
    #pragma unroll
    for (int s = 0; s < 4; ++s)
        a[s] = *(const short8*)(A + (size_t)r * K + s * 32 + quad * 8);
    const int r0 = rowbase + quad * 4;
    for (int ny = 0; ny < 4; ++ny) {
        __syncthreads();
        for (int i = tid; i < 64 * 16; i += 256) {
            int row = i >> 4, off = (i & 15) * 8;
            *(short8*)(Bs + row * KP + off) = *(const short8*)(Bt + (size_t)(ny * 64 + row) * K + off);
        }
        __syncthreads();
        floatx4 acc[4] = {};
        #pragma unroll
        for (int f = 0; f < 4; ++f) {
            const ushort_t* bp = Bs + (f * 16 + ln) * KP + quad * 8;
            #pragma unroll
            for (int s = 0; s < 4; ++s) {
                short8 b = *(const short8*)(bp + s * 32);
                acc[f] = __builtin_amdgcn_mfma_f32_16x16x32_bf16(a[s], b, acc[f], 0, 0, 0);
            }
        }
        #pragma unroll
        for (int f = 0; f < 4; ++f) {
            int n = ny * 64 + f * 16 + ln;
            float bias = b1[n];
            #pragma unroll
            for (int g = 0; g < 4; ++g) {
                int rr = r0 + g;
                if (rr >= N_NODES) continue;
                h1[(size_t)rr * 256 + n] = f2bf(fmaxf(acc[f][g] + bias, 0.0f));
            }
        }
    }
}

// ---------------- gemm2: [t2 | r2] = h1 @ [W2_rel | W2_root], both bf16 [N][128] ----------------
__global__ __launch_bounds__(256) void gemm2_mfma(
    const ushort_t* __restrict__ A, const ushort_t* __restrict__ Bt,
    ushort_t* __restrict__ t2, ushort_t* __restrict__ r2) {
    constexpr int K = 256, KP = K + 8;
    __shared__ ushort_t Bs[64 * KP];
    const int tid = threadIdx.x;
    const int w = tid >> 6, lane = tid & 63;
    const int ln = lane & 15, quad = lane >> 4;
    const int rowbase = blockIdx.x * 64 + w * 16;
    int r = rowbase + ln; if (r > N_NODES - 1) r = N_NODES - 1;
    short8 a[8];
    #pragma unroll
    for (int s = 0; s < 8; ++s)
        a[s] = *(const short8*)(A + (size_t)r * K + s * 32 + quad * 8);
    const int r0 = rowbase + quad * 4;
    for (int ny = 0; ny < 4; ++ny) {
        __syncthreads();
        for (int i = tid; i < 64 * 32; i += 256) {
            int row = i >> 5, off = (i & 31) * 8;
            *(short8*)(Bs + row * KP + off) = *(const short8*)(Bt + (size_t)(ny * 64 + row) * K + off);
        }
        __syncthreads();
        floatx4 acc[4] = {};
        #pragma unroll
        for (int f = 0; f < 4; ++f) {
            const ushort_t* bp = Bs + (f * 16 + ln) * KP + quad * 8;
            #pragma unroll
            for (int s = 0; s < 8; ++s) {
                short8 b = *(const short8*)(bp + s * 32);
                acc[f] = __builtin_amdgcn_mfma_f32_16x16x32_bf16(a[s], b, acc[f], 0, 0, 0);
            }
        }
        #pragma unroll
        for (int f = 0; f < 4; ++f) {
            int n = ny * 64 + f * 16 + ln;
            #pragma unroll
            for (int g = 0; g < 4; ++g) {
                int rr = r0 + g;
                if (rr >= N_NODES) continue;
                ushort_t v = f2bf(acc[f][g]);
                if (n < 128) t2[(size_t)rr * 128 + n] = v;
                else r2[(size_t)rr * 128 + (n - 128)] = v;
            }
        }
    }
}

// ---------------- fused gather2 + combine + gemm3 (32 nodes/block, 8 threads/node) ----------------
// Phase 1: h2 row = relu(mean-gather(t2) + r2 + b2) -> LDS As (bf16), 8 threads/node x 16 ch.
// Phase 2: MFMA M=32,N=64,K=128; wave w -> row-tile (w&1), col-tile (w>>1); B3t from global.
__global__ __launch_bounds__(256) void g2g3_kernel(
    const ushort_t* __restrict__ t2, const ushort_t* __restrict__ r2,
    const int* __restrict__ row_beg, const int* __restrict__ row_end,
    const ushort_t* __restrict__ eidx, const float* __restrict__ dinv,
    const float* __restrict__ b2, const ushort_t* __restrict__ B3t,
    ushort_t* __restrict__ tml, float* __restrict__ rml) {
    constexpr int KP = 136;
    __shared__ ushort_t As[32 * KP];
    const int tid = threadIdx.x;
    const int nb = blockIdx.x * 32;
    // phase 1
    {
        const int nl = tid >> 3, lane = tid & 7;
        int node = nb + nl; if (node > N_NODES - 1) node = N_NODES - 1;
        const int beg = row_beg[node], end = row_end[node];
        float a0[16] = {}, a1[16] = {};
        int j = beg;
        for (; j + 1 < end; j += 2) {
            const ushort_t* p0 = t2 + (size_t)eidx[j] * 128 + lane * 16;
            const ushort_t* p1 = t2 + (size_t)eidx[j + 1] * 128 + lane * 16;
            short8 u0 = *(const short8*)(p0), u1 = *(const short8*)(p0 + 8);
            short8 w0 = *(const short8*)(p1), w1 = *(const short8*)(p1 + 8);
            #pragma unroll
            for (int i = 0; i < 8; ++i) {
                a0[i] += bf2f((ushort_t)u0[i]); a0[8 + i] += bf2f((ushort_t)u1[i]);
                a1[i] += bf2f((ushort_t)w0[i]); a1[8 + i] += bf2f((ushort_t)w1[i]);
            }
        }
        if (j < end) {
            const ushort_t* p0 = t2 + (size_t)eidx[j] * 128 + lane * 16;
            short8 u0 = *(const short8*)(p0), u1 = *(const short8*)(p0 + 8);
            #pragma unroll
            for (int i = 0; i < 8; ++i) { a0[i] += bf2f((ushort_t)u0[i]); a0[8 + i] += bf2f((ushort_t)u1[i]); }
        }
        float d = dinv[node];
        const ushort_t* rp = r2 + (size_t)node * 128 + lane * 16;
        short8 rv0 = *(const short8*)(rp), rv1 = *(const short8*)(rp + 8);
        const float* bp = b2 + lane * 16;
        float4 ba = ld4(bp), bb = ld4(bp + 4), bc4 = ld4(bp + 8), bd4 = ld4(bp + 12);
        float bc[16] = {ba.x, ba.y, ba.z, ba.w, bb.x, bb.y, bb.z, bb.w,
                        bc4.x, bc4.y, bc4.z, bc4.w, bd4.x, bd4.y, bd4.z, bd4.w};
        short8 o0, o1;
        #pragma unroll
        for (int i = 0; i < 8; ++i) {
            o0[i] = f2bf(fmaxf((a0[i] + a1[i]) * d + bf2f((ushort_t)rv0[i]) + bc[i], 0.0f));
            o1[i] = f2bf(fmaxf((a0[8 + i] + a1[8 + i]) * d + bf2f((ushort_t)rv1[i]) + bc[8 + i], 0.0f));
        }
        ushort_t* ap = As + nl * KP + lane * 16;
        *(short8*)(ap) = o0;
        *(short8*)(ap + 8) = o1;
    }
    __syncthreads();
    // phase 2: M=32, N=64, K=128
    const int w = tid >> 6, lane64 = tid & 63;
    const int ln = lane64 & 15, quad = lane64 >> 4;
    const int rowt = (w & 1) * 16;
    const int colt = (w >> 1) * 32;
    short8 a[4];
    #pragma unroll
    for (int s = 0; s < 4; ++s)
        a[s] = *(const short8*)(As + (rowt + ln) * KP + s * 32 + quad * 8);
    floatx4 acc[2] = {};
    #pragma unroll
    for (int fc = 0; fc < 2; ++fc) {
        const ushort_t* bp = B3t + (size_t)(colt + fc * 16 + ln) * 128 + quad * 8;
        #pragma unroll
        for (int s = 0; s < 4; ++s) {
            short8 b = *(const short8*)(bp + s * 32);
            acc[fc] = __builtin_amdgcn_mfma_f32_16x16x32_bf16(a[s], b, acc[fc], 0, 0, 0);
        }
    }
    const int r0 = nb + rowt + quad * 4;
    #pragma unroll
    for (int fc = 0; fc < 2; ++fc) {
        int ncol = colt + fc * 16 + ln;
        #pragma unroll
        for (int g = 0; g < 4; ++g) {
            int rr = r0 + g;
            if (rr >= N_NODES) continue;
            float v = acc[fc][g];
            if (ncol < 32) tml[(size_t)rr * 32 + ncol] = f2bf(v);
            else rml[(size_t)rr * 32 + (ncol - 32)] = v;
        }
    }
}

// ---------------- gather 3 (fused combine + split write) ----------------
__global__ __launch_bounds__(256) void gather3_kernel(
    const ushort_t* __restrict__ tml, const float* __restrict__ rml,
    const int* __restrict__ row_beg, const int* __restrict__ row_end,
    const ushort_t* __restrict__ eidx, const float* __restrict__ dinv,
    const float* __restrict__ bmu, const float* __restrict__ bls,
    float* __restrict__ out) {
    const int lane = threadIdx.x & 3;
    const int nl = threadIdx.x >> 2;
    const int n = blockIdx.x * 64 + nl;
    if (n >= N_NODES) return;
    const int beg = row_beg[n], end = row_end[n];
    float a0[8] = {}, a1[8] = {};
    int j = beg;
    for (; j + 1 < end; j += 2) {
        int s0 = eidx[j], s1 = eidx[j + 1];
        short8 v0 = *(const short8*)(tml + (size_t)s0 * 32 + lane * 8);
        short8 v1 = *(const short8*)(tml + (size_t)s1 * 32 + lane * 8);
        #pragma unroll
        for (int i = 0; i < 8; ++i) { a0[i] += bf2f((ushort_t)v0[i]); a1[i] += bf2f((ushort_t)v1[i]); }
    }
    if (j < end) {
        int s0 = eidx[j];
        short8 v0 = *(const short8*)(tml + (size_t)s0 * 32 + lane * 8);
        #pragma unroll
        for (int i = 0; i < 8; ++i) a0[i] += bf2f((ushort_t)v0[i]);
    }
    float d = dinv[n];
    const float* bias = (lane < 2) ? (bmu + lane * 8) : (bls + (lane - 2) * 8);
    float4 ra = ld4(rml + (size_t)n * 32 + lane * 8);
    float4 rb = ld4(rml + (size_t)n * 32 + lane * 8 + 4);
    float4 ba = ld4(bias);
    float4 bb = ld4(bias + 4);
    float rr[8] = {ra.x, ra.y, ra.z, ra.w, rb.x, rb.y, rb.z, rb.w};
    float bc[8] = {ba.x, ba.y, ba.z, ba.w, bb.x, bb.y, bb.z, bb.w};
    float res[8];
    #pragma unroll
    for (int i = 0; i < 8; ++i) res[i] = (a0[i] + a1[i]) * d + rr[i] + bc[i];
    float* base = (lane < 2) ? (out + (size_t)n * 16 + lane * 8)
                             : (out + 800000u + (size_t)n * 16 + (lane - 2) * 8);
    *(float4*)(base) = make_float4(res[0], res[1], res[2], res[3]);
    *(float4*)(base + 4) = make_float4(res[4], res[5], res[6], res[7]);
}

extern "C" void kernel_launch(void* const* d_in, const int* in_sizes, int n_in,
                              void* d_out, int out_size, void* d_ws, size_t ws_size,
                              hipStream_t stream) {
    const float* x       = (const float*)d_in[0];
    const float* W1_rel  = (const float*)d_in[1];
    const float* b1      = (const float*)d_in[2];
    const float* W1_root = (const float*)d_in[3];
    const float* W2_rel  = (const float*)d_in[4];
    const float* b2      = (const float*)d_in[5];
    const float* W2_root = (const float*)d_in[6];
    const float* Wmu_rel = (const float*)d_in[7];
    const float* bmu     = (const float*)d_in[8];
    const float* Wmu_root= (const float*)d_in[9];
    const float* Wls_rel = (const float*)d_in[10];
    const float* bls     = (const float*)d_in[11];
    const float* Wls_root= (const float*)d_in[12];
    const int*   ei      = (const int*)d_in[13];
    const int* src = ei;
    const int* dst = ei + N_EDGES;

    // ---- workspace layout ----
    int*      bcursor = (int*)d_ws;                      //       256
    int*      row_beg = bcursor + 256;                   //    50,048
    int*      row_end = row_beg + 50048;                 //    50,048
    unsigned* pairbuf = (unsigned*)(row_end + 50048);    // 1,003,520
    ushort_t* eidx    = (ushort_t*)(pairbuf + 1003520);  // 1,003,520 ush
    float*    dinv    = (float*)(eidx + 1003520);        //    50,000
    ushort_t* ax   = (ushort_t*)(dinv + 50000);          //  6,400,000  [N,128]: [agg | x]
    ushort_t* h1   = ax + 6400000;                       // 12,800,000  [N,256]
    ushort_t* t2   = h1 + 12800000;                      //  6,400,000  [N,128] bf16
    ushort_t* r2   = t2 + 6400000;                       //  6,400,000  [N,128] bf16
    ushort_t* tml  = r2 + 6400000;                       //  1,600,000  [N,32]  bf16
    ushort_t* B1t  = tml + 1600000;                      //     32,768
    ushort_t* B2t  = B1t + 32768;                        //     65,536
    ushort_t* B3t  = B2t + 65536;                        //      8,192
    float* rml     = (float*)(B3t + 8192);               //  1,600,000  [N,32] f32
    float* out     = (float*)d_out;

    // ---- prep + CSR build ----
    prep_kernel<<<1980, 256, 0, stream>>>(x, W1_rel, W1_root, W2_rel, W2_root,
                                          Wmu_rel, Wls_rel, Wmu_root, Wls_root,
                                          ax, B1t, B2t, B3t, bcursor);
    partition_kernel<<<PBLK, 256, 0, stream>>>(src, dst, bcursor, pairbuf);
    fill_bucket_kernel<<<NBUCK, 256, 0, stream>>>(pairbuf, bcursor, row_beg, row_end, dinv, eidx);

    // ---- layer 1 ----
    gather1_kernel<<<1563, 256, 0, stream>>>(row_beg, row_end, eidx, dinv, ax);
    gemm1_mfma<<<782, 256, 0, stream>>>(ax, B1t, b1, h1);

    // ---- layer 2 + fused layer-3 transform ----
    gemm2_mfma<<<782, 256, 0, stream>>>(h1, B2t, t2, r2);
    g2g3_kernel<<<1563, 256, 0, stream>>>(t2, r2, row_beg, row_end, eidx, dinv, b2, B3t, tml, rml);

    // ---- mu / logstd final aggregation ----
    gather3_kernel<<<782, 256, 0, stream>>>(tml, rml, row_beg, row_end, eidx, dinv, bmu, bls, out);
}